// Round 6
// baseline (223.300 us; speedup 1.0000x reference)
//
#include <hip/hip_runtime.h>

#define NN 10000
#define NE 40000

typedef __attribute__((ext_vector_type(8))) short bf16x8;
typedef __attribute__((ext_vector_type(4))) float f32x4;
typedef __attribute__((ext_vector_type(8))) unsigned short u16x8;

__device__ inline unsigned short bf16rne(float f) {
  union { float f; unsigned u; } v; v.f = f;
  return (unsigned short)((v.u + 0x7FFFu + ((v.u >> 16) & 1u)) >> 16);
}

// ew2 [128 x 2048] f32 -> bf16 MFMA-B fragment order.
// elem j of lane l, col-tile ct, k-chunk kk = B[kk*32+(l>>4)*8+j][ct*16+(l&15)]
// at ushort index ct*2048 + kk*512 + l*8 + j.
__global__ void k_reorder(const float* __restrict__ ew2, unsigned short* __restrict__ out) {
  const int l  = threadIdx.x & 63;
  const int kk = threadIdx.x >> 6;
  const int ct = blockIdx.x;
  const int col = ct * 16 + (l & 15);
  const int g = l >> 4;
  u16x8 v;
#pragma unroll
  for (int j = 0; j < 8; ++j) v[j] = bf16rne(ew2[(kk * 32 + g * 8 + j) * 2048 + col]);
  *reinterpret_cast<u16x8*>(out + ((size_t)(ct * 2048 + kk * 512 + l * 8))) = v;
}

// ew1 [16 x 128] f32 -> bf16 B-frag, K padded to 32 with zeros. 8 col-tiles.
__global__ void k_reorder_e(const float* __restrict__ ew1, unsigned short* __restrict__ out) {
  const int l  = threadIdx.x & 63;
  const int ct = threadIdx.x >> 6;  // 512 threads -> 8 tiles
  const int g = l >> 4;
  u16x8 v;
#pragma unroll
  for (int j = 0; j < 8; ++j) {
    int k = g * 8 + j;
    v[j] = (k < 16) ? bf16rne(ew1[k * 128 + ct * 16 + (l & 15)]) : (unsigned short)0;
  }
  *reinterpret_cast<u16x8*>(out + ((size_t)(ct * 64 + l) * 8)) = v;
}

// out[n,KO] = (relu?)(xin[n,KI]) @ root[KI,KO] + bias[KO]
template <int KI, int KO, bool RELU_IN>
__global__ void k_root(const float* __restrict__ xin, const float* __restrict__ root,
                       const float* __restrict__ bias, float* __restrict__ out) {
  int idx = blockIdx.x * 256 + threadIdx.x;
  if (idx >= NN * KO) return;
  int n = idx / KO, o = idx % KO;
  float acc = bias[o];
#pragma unroll
  for (int k = 0; k < KI; ++k) {
    float v = xin[n * KI + k];
    if (RELU_IN) v = fmaxf(v, 0.f);
    acc += v * root[k * KO + o];
  }
  out[idx] = acc;
}

// Fused per-edge kernel, col-group split grid: 625 edge-groups x 4 col-groups.
// Block: 64 edges x (16 ocols x 32 i-values). 4 waves; wave w handles i-subset
// ii = w+4t, t in [0,8). H recomputed per block via MFMA. Wave partials
// combined in LDS (aliased over dead hfrag), one coalesced atomic per (e,ocol).
// L1 (CI=32): cg in [0,4): ocol=cg*16+c16, i=ii,      ct=i*4+cg
// L2 (CI=64): h=cg&1,p=cg>>1: ocol=h*16+c16, i=p+2*ii, ct=i*2+h (p-dup atomics)
template <int CI, int CO, bool RELU_IN>
__global__ __launch_bounds__(256, 4) void k_edge(
    const int* __restrict__ src, const int* __restrict__ dst,
    const float* __restrict__ eattr,
    const unsigned short* __restrict__ ew1f, const float* __restrict__ eb1,
    const unsigned short* __restrict__ bfrag, const float* __restrict__ eb2,
    const float* __restrict__ xin, float* __restrict__ aggr) {
  constexpr int TE = 64;
  const int tid = threadIdx.x;
  const int eg = blockIdx.x >> 2, cg = blockIdx.x & 3;
  const int e0 = eg * TE;
  const int h = cg & 1, p = cg >> 1;  // used when CI==64

  __shared__ int s_src[TE];
  __shared__ int s_dst[TE];
  __shared__ float s_x[32][68];          // [ii][edge], rows 16B-aligned
  __shared__ float s_arena[4 * 64 * 17]; // 17.4 KB combine buf; hfrag aliases it
  unsigned short* s_hfrag = reinterpret_cast<unsigned short*>(s_arena);

  if (tid < TE) { s_src[tid] = src[e0 + tid]; s_dst[tid] = dst[e0 + tid]; }
  __syncthreads();

  // gather x[src] -> s_x[ii][e]; c = ii (L1) or p+2*ii (L2)
  for (int idx = tid; idx < TE * 32; idx += 256) {
    const int e = idx >> 5, ii = idx & 31;
    const int c = (CI == 32) ? ii : (p + 2 * ii);
    float v = xin[(size_t)s_src[e] * CI + c];
    if (RELU_IN) v = fmaxf(v, 0.f);
    s_x[ii][e] = v;
  }

  const int l = tid & 63, w = tid >> 6, g = l >> 4, c16 = l & 15;

  // ---- H phase via MFMA: wave w -> edge tile m=w, all 128 channels (8 MFMAs)
  {
    const int m = w;
    bf16x8 ea;
#pragma unroll
    for (int j = 0; j < 8; ++j) ea[j] = 0;
    if (g < 2) {
      const float* pp = eattr + (size_t)(e0 + 16 * m + c16) * 16 + g * 8;
      f32x4 v0 = *reinterpret_cast<const f32x4*>(pp);
      f32x4 v1 = *reinterpret_cast<const f32x4*>(pp + 4);
#pragma unroll
      for (int j = 0; j < 4; ++j) { ea[j] = bf16rne(v0[j]); ea[4 + j] = bf16rne(v1[j]); }
    }
#pragma unroll
    for (int ct = 0; ct < 8; ++ct) {
      bf16x8 bw = *reinterpret_cast<const bf16x8*>(ew1f + (size_t)(ct * 64 + l) * 8);
      const float bb = eb1[ct * 16 + c16];
      f32x4 acc = {bb, bb, bb, bb};
      acc = __builtin_amdgcn_mfma_f32_16x16x32_bf16(ea, bw, acc, 0, 0, 0);
#pragma unroll
      for (int r = 0; r < 4; ++r) {
        const int c = ct * 16 + c16;
        s_hfrag[(((m * 4) + (c >> 5)) * 64 + ((c >> 3) & 3) * 16 + g * 4 + r) * 8 + (c & 7)] =
            bf16rne(fmaxf(acc[r], 0.f));
      }
    }
  }
  __syncthreads();

  // A fragments reg-resident (linear conflict-free b128 reads)
  bf16x8 afrag[4][4];
#pragma unroll
  for (int m = 0; m < 4; ++m)
#pragma unroll
    for (int kk = 0; kk < 4; ++kk)
      afrag[m][kk] = *reinterpret_cast<const bf16x8*>(&s_hfrag[((m * 4 + kk) * 64 + l) * 8]);
  __syncthreads();  // hfrag reads done: arena reusable after t-loop

  float msg[4][4];
#pragma unroll
  for (int m = 0; m < 4; ++m)
#pragma unroll
    for (int r = 0; r < 4; ++r) msg[m][r] = 0.f;

  const int ocol = ((CI == 32) ? cg : h) * 16 + c16;
  const bf16x8* Bb = reinterpret_cast<const bf16x8*>(bfrag);

  bf16x8 bA[4], bB[4];
  float bbA, bbB;

#define PREF(T, BUF, BBV)                                                        \
  {                                                                              \
    const int ii_ = w + 4 * (T);                                                 \
    const int i_ = (CI == 32) ? ii_ : (p + 2 * ii_);                             \
    const int ct_ = (CI == 32) ? (i_ * 4 + cg) : (i_ * 2 + h);                   \
    const bf16x8* bp_ = Bb + (size_t)ct_ * 256 + l;                              \
    _Pragma("unroll") for (int kk = 0; kk < 4; ++kk) BUF[kk] = bp_[kk * 64];     \
    BBV = eb2[i_ * CO + ocol];                                                   \
  }

#define COMP(T, BUF, BBV)                                                        \
  {                                                                              \
    const int ii_ = w + 4 * (T);                                                 \
    _Pragma("unroll") for (int m = 0; m < 4; ++m) {                              \
      f32x4 wacc = {0.f, 0.f, 0.f, 0.f};                                         \
      _Pragma("unroll") for (int kk = 0; kk < 4; ++kk)                           \
          wacc = __builtin_amdgcn_mfma_f32_16x16x32_bf16(afrag[m][kk], BUF[kk],  \
                                                         wacc, 0, 0, 0);         \
      const f32x4 xs = *reinterpret_cast<const f32x4*>(&s_x[ii_][m * 16 + g * 4]);\
      _Pragma("unroll") for (int r = 0; r < 4; ++r)                              \
          msg[m][r] += fmaxf(wacc[r] + BBV, 0.f) * xs[r];                        \
    }                                                                            \
  }

  PREF(0, bA, bbA)
#pragma unroll 1
  for (int t = 0; t < 6; t += 2) {
    PREF(t + 1, bB, bbB)
    COMP(t, bA, bbA)
    PREF(t + 2, bA, bbA)
    COMP(t + 1, bB, bbB)
  }
  PREF(7, bB, bbB)
  COMP(6, bA, bbA)
  COMP(7, bB, bbB)
#undef PREF
#undef COMP

  // ---- combine 4 wave-partials in LDS, then one atomic per (e,ocol)
#pragma unroll
  for (int m = 0; m < 4; ++m)
#pragma unroll
    for (int r = 0; r < 4; ++r)
      s_arena[w * 1088 + (m * 16 + g * 4 + r) * 17 + c16] = msg[m][r];
  __syncthreads();

  {
    const int eb_ = tid >> 4, cc = tid & 15;
#pragma unroll
    for (int q = 0; q < 4; ++q) {
      const int e = eb_ + q * 16;
      float v = s_arena[e * 17 + cc] + s_arena[1088 + e * 17 + cc] +
                s_arena[2176 + e * 17 + cc] + s_arena[3264 + e * 17 + cc];
      atomicAdd(&aggr[(size_t)s_dst[e] * CO + ((CI == 32) ? cg : h) * 16 + cc], v);
    }
  }
}

extern "C" void kernel_launch(void* const* d_in, const int* in_sizes, int n_in,
                              void* d_out, int out_size, void* d_ws, size_t ws_size,
                              hipStream_t stream) {
  const float* x       = (const float*)d_in[0];
  const int*   ei      = (const int*)d_in[1];
  const float* eattr   = (const float*)d_in[2];
  const float* l1_ew1  = (const float*)d_in[3];
  const float* l1_eb1  = (const float*)d_in[4];
  const float* l1_ew2  = (const float*)d_in[5];
  const float* l1_eb2  = (const float*)d_in[6];
  const float* l1_root = (const float*)d_in[7];
  const float* l1_bias = (const float*)d_in[8];
  const float* l2_ew1  = (const float*)d_in[9];
  const float* l2_eb1  = (const float*)d_in[10];
  const float* l2_ew2  = (const float*)d_in[11];
  const float* l2_eb2  = (const float*)d_in[12];
  const float* l2_root = (const float*)d_in[13];
  const float* l2_bias = (const float*)d_in[14];

  const int* src = ei;
  const int* dst = ei + NE;

  float* P1 = (float*)d_ws;                                // [N,64] pre-relu L1 out
  unsigned short* B1  = (unsigned short*)(P1 + NN * 64);   // 2048*128 bf16 ew2 frag
  unsigned short* B2  = B1 + 2048 * 128;
  unsigned short* B1e = B2 + 2048 * 128;                   // 8*64*8 bf16 ew1 frag
  unsigned short* B2e = B1e + 8 * 64 * 8;
  float* outf = (float*)d_out;

  k_reorder<<<128, 256, 0, stream>>>(l1_ew2, B1);
  k_reorder<<<128, 256, 0, stream>>>(l2_ew2, B2);
  k_reorder_e<<<1, 512, 0, stream>>>(l1_ew1, B1e);
  k_reorder_e<<<1, 512, 0, stream>>>(l2_ew1, B2e);

  k_root<32, 64, false><<<(NN * 64 + 255) / 256, 256, 0, stream>>>(x, l1_root, l1_bias, P1);
  k_edge<32, 64, false><<<4 * NE / 64, 256, 0, stream>>>(src, dst, eattr, B1e, l1_eb1, B1, l1_eb2, x, P1);
  k_root<64, 32, true><<<(NN * 32 + 255) / 256, 256, 0, stream>>>(P1, l2_root, l2_bias, outf);
  k_edge<64, 32, true><<<4 * NE / 64, 256, 0, stream>>>(src, dst, eattr, B2e, l2_eb1, B2, l2_eb2, P1, outf);
}

// Round 7
// 97.687 us; speedup vs baseline: 2.2859x; 2.2859x over previous
//
#include <hip/hip_runtime.h>

#define NN 10000
#define NE 40000

typedef __attribute__((ext_vector_type(8))) short bf16x8;
typedef __attribute__((ext_vector_type(4))) float f32x4;
typedef __attribute__((ext_vector_type(8))) unsigned short u16x8;

__device__ inline unsigned short bf16rne(float f) {
  union { float f; unsigned u; } v; v.f = f;
  return (unsigned short)((v.u + 0x7FFFu + ((v.u >> 16) & 1u)) >> 16);
}

// ew2 [128 x 2048] f32 -> bf16 MFMA-B fragment order.
// elem j of lane l, col-tile ct, k-chunk kk = B[kk*32+(l>>4)*8+j][ct*16+(l&15)]
// at ushort index ct*2048 + kk*512 + l*8 + j.
__global__ void k_reorder(const float* __restrict__ ew2, unsigned short* __restrict__ out) {
  const int l  = threadIdx.x & 63;
  const int kk = threadIdx.x >> 6;
  const int ct = blockIdx.x;
  const int col = ct * 16 + (l & 15);
  const int g = l >> 4;
  u16x8 v;
#pragma unroll
  for (int j = 0; j < 8; ++j) v[j] = bf16rne(ew2[(kk * 32 + g * 8 + j) * 2048 + col]);
  *reinterpret_cast<u16x8*>(out + ((size_t)(ct * 2048 + kk * 512 + l * 8))) = v;
}

// ew1 [16 x 128] f32 -> bf16 B-frag, K padded to 32 with zeros. 8 col-tiles.
__global__ void k_reorder_e(const float* __restrict__ ew1, unsigned short* __restrict__ out) {
  const int l  = threadIdx.x & 63;
  const int ct = threadIdx.x >> 6;  // 512 threads -> 8 tiles
  const int g = l >> 4;
  u16x8 v;
#pragma unroll
  for (int j = 0; j < 8; ++j) {
    int k = g * 8 + j;
    v[j] = (k < 16) ? bf16rne(ew1[k * 128 + ct * 16 + (l & 15)]) : (unsigned short)0;
  }
  *reinterpret_cast<u16x8*>(out + ((size_t)(ct * 64 + l) * 8)) = v;
}

// out[n,KO] = (relu?)(xin[n,KI]) @ root[KI,KO] + bias[KO]
template <int KI, int KO, bool RELU_IN>
__global__ void k_root(const float* __restrict__ xin, const float* __restrict__ root,
                       const float* __restrict__ bias, float* __restrict__ out) {
  int idx = blockIdx.x * 256 + threadIdx.x;
  if (idx >= NN * KO) return;
  int n = idx / KO, o = idx % KO;
  float acc = bias[o];
#pragma unroll
  for (int k = 0; k < KI; ++k) {
    float v = xin[n * KI + k];
    if (RELU_IN) v = fmaxf(v, 0.f);
    acc += v * root[k * KO + o];
  }
  out[idx] = acc;
}

// Fused per-edge kernel: 64 edges/block, 8 waves (512 thr), 625 blocks.
// Wave decomposition splits EDGE ROWS (mh) and o-tiles across waves, so each
// (e,ocol) is owned by one wave (L1) / two waves with dup atomics (L2).
// No combine phase. Atomic pattern identical to R3's proven coalesced one:
// 16 contiguous lanes = 16 contiguous cols of one edge, full row in one block.
// L1 (CI=32,CO=64): wave=(mh=w>>2, ot=w&3); i=t (32 iters), ct=i*4+ot
// L2 (CI=64,CO=32): wave=(mh=w>>2, ot=(w>>1)&1, ip=w&1); i=ip+2t, ct=i*2+ot
template <int CI, int CO, bool RELU_IN>
__global__ __launch_bounds__(512, 4) void k_edge(
    const int* __restrict__ src, const int* __restrict__ dst,
    const float* __restrict__ eattr,
    const unsigned short* __restrict__ ew1f, const float* __restrict__ eb1,
    const unsigned short* __restrict__ bfrag, const float* __restrict__ eb2,
    const float* __restrict__ xin, float* __restrict__ aggr) {
  constexpr int TE = 64;
  const int tid = threadIdx.x;
  const int e0 = blockIdx.x * TE;

  __shared__ int s_src[TE];
  __shared__ int s_dst[TE];
  __shared__ float s_x[CI][68];
  __shared__ unsigned short s_hfrag[16 * 64 * 8];  // 16 KB

  if (tid < TE) { s_src[tid] = src[e0 + tid]; s_dst[tid] = dst[e0 + tid]; }
  __syncthreads();

  // gather x[src] -> transposed LDS (coalesced: 64 lanes span full rows)
  for (int idx = tid; idx < TE * CI; idx += 512) {
    const int e = idx / CI, c = idx % CI;
    float v = xin[(size_t)s_src[e] * CI + c];
    if (RELU_IN) v = fmaxf(v, 0.f);
    s_x[c][e] = v;
  }

  const int l = tid & 63, w = tid >> 6, g = l >> 4, c16 = l & 15;

  // ---- H phase via MFMA: wave w -> edge tile m=w>>1, channel half w&1
  {
    const int m = w >> 1;
    bf16x8 ea;
#pragma unroll
    for (int j = 0; j < 8; ++j) ea[j] = 0;
    if (g < 2) {
      const float* p = eattr + (size_t)(e0 + 16 * m + c16) * 16 + g * 8;
      f32x4 v0 = *reinterpret_cast<const f32x4*>(p);
      f32x4 v1 = *reinterpret_cast<const f32x4*>(p + 4);
#pragma unroll
      for (int j = 0; j < 4; ++j) { ea[j] = bf16rne(v0[j]); ea[4 + j] = bf16rne(v1[j]); }
    }
#pragma unroll
    for (int q = 0; q < 4; ++q) {
      const int ct = (w & 1) * 4 + q;
      bf16x8 bw = *reinterpret_cast<const bf16x8*>(ew1f + (size_t)(ct * 64 + l) * 8);
      const float bb = eb1[ct * 16 + c16];
      f32x4 acc = {bb, bb, bb, bb};
      acc = __builtin_amdgcn_mfma_f32_16x16x32_bf16(ea, bw, acc, 0, 0, 0);
#pragma unroll
      for (int r = 0; r < 4; ++r) {
        const int c = ct * 16 + c16;
        s_hfrag[(((m * 4) + (c >> 5)) * 64 + ((c >> 3) & 3) * 16 + g * 4 + r) * 8 + (c & 7)] =
            bf16rne(fmaxf(acc[r], 0.f));
      }
    }
  }
  __syncthreads();

  const int mh = w >> 2;

  // A fragments for this wave's 32 edges (2 m-tiles), conflict-free b128 reads
  bf16x8 afrag[2][4];
#pragma unroll
  for (int mm = 0; mm < 2; ++mm)
#pragma unroll
    for (int kk = 0; kk < 4; ++kk)
      afrag[mm][kk] =
          *reinterpret_cast<const bf16x8*>(&s_hfrag[(((mh * 2 + mm) * 4 + kk) * 64 + l) * 8]);

  float msg[2][4];
#pragma unroll
  for (int mm = 0; mm < 2; ++mm)
#pragma unroll
    for (int r = 0; r < 4; ++r) msg[mm][r] = 0.f;

  const int ot = (CI == 32) ? (w & 3) : ((w >> 1) & 1);
  const int ocol = ot * 16 + c16;
  const bf16x8* Bb = reinterpret_cast<const bf16x8*>(bfrag);

  bf16x8 bA[4], bB[4];
  float bbA, bbB;

#define PREF(T, BUF, BBV)                                                        \
  {                                                                              \
    const int i_ = (CI == 32) ? (T) : ((w & 1) + 2 * (T));                       \
    const int ct_ = (CI == 32) ? ((T) * 4 + ot) : (i_ * 2 + ot);                 \
    const bf16x8* bp_ = Bb + (size_t)ct_ * 256 + l;                              \
    _Pragma("unroll") for (int kk = 0; kk < 4; ++kk) BUF[kk] = bp_[kk * 64];     \
    BBV = eb2[i_ * CO + ocol];                                                   \
  }

#define COMP(T, BUF, BBV)                                                        \
  {                                                                              \
    const int i_ = (CI == 32) ? (T) : ((w & 1) + 2 * (T));                       \
    _Pragma("unroll") for (int mm = 0; mm < 2; ++mm) {                           \
      f32x4 wacc = {0.f, 0.f, 0.f, 0.f};                                         \
      _Pragma("unroll") for (int kk = 0; kk < 4; ++kk)                           \
          wacc = __builtin_amdgcn_mfma_f32_16x16x32_bf16(afrag[mm][kk], BUF[kk], \
                                                         wacc, 0, 0, 0);         \
      const f32x4 xs = *reinterpret_cast<const f32x4*>(                          \
          &s_x[i_][(mh * 2 + mm) * 16 + g * 4]);                                 \
      _Pragma("unroll") for (int r = 0; r < 4; ++r)                              \
          msg[mm][r] += fmaxf(wacc[r] + BBV, 0.f) * xs[r];                       \
    }                                                                            \
  }

  PREF(0, bA, bbA)
#pragma unroll 1
  for (int t = 0; t < 30; t += 2) {
    PREF(t + 1, bB, bbB)
    COMP(t, bA, bbA)
    PREF(t + 2, bA, bbA)
    COMP(t + 1, bB, bbB)
  }
  PREF(31, bB, bbB)
  COMP(30, bA, bbA)
  COMP(31, bB, bbB)
#undef PREF
#undef COMP

  // coalesced atomics: per instr, 4 edges (g) x 16 contiguous cols (64B runs)
#pragma unroll
  for (int mm = 0; mm < 2; ++mm)
#pragma unroll
    for (int r = 0; r < 4; ++r)
      atomicAdd(&aggr[(size_t)s_dst[mh * 32 + mm * 16 + g * 4 + r] * CO + ocol], msg[mm][r]);
}

extern "C" void kernel_launch(void* const* d_in, const int* in_sizes, int n_in,
                              void* d_out, int out_size, void* d_ws, size_t ws_size,
                              hipStream_t stream) {
  const float* x       = (const float*)d_in[0];
  const int*   ei      = (const int*)d_in[1];
  const float* eattr   = (const float*)d_in[2];
  const float* l1_ew1  = (const float*)d_in[3];
  const float* l1_eb1  = (const float*)d_in[4];
  const float* l1_ew2  = (const float*)d_in[5];
  const float* l1_eb2  = (const float*)d_in[6];
  const float* l1_root = (const float*)d_in[7];
  const float* l1_bias = (const float*)d_in[8];
  const float* l2_ew1  = (const float*)d_in[9];
  const float* l2_eb1  = (const float*)d_in[10];
  const float* l2_ew2  = (const float*)d_in[11];
  const float* l2_eb2  = (const float*)d_in[12];
  const float* l2_root = (const float*)d_in[13];
  const float* l2_bias = (const float*)d_in[14];

  const int* src = ei;
  const int* dst = ei + NE;

  float* P1 = (float*)d_ws;                                // [N,64] pre-relu L1 out
  unsigned short* B1  = (unsigned short*)(P1 + NN * 64);   // 2048*128 bf16 ew2 frag
  unsigned short* B2  = B1 + 2048 * 128;
  unsigned short* B1e = B2 + 2048 * 128;                   // 8*64*8 bf16 ew1 frag
  unsigned short* B2e = B1e + 8 * 64 * 8;
  float* outf = (float*)d_out;

  k_reorder<<<128, 256, 0, stream>>>(l1_ew2, B1);
  k_reorder<<<128, 256, 0, stream>>>(l2_ew2, B2);
  k_reorder_e<<<1, 512, 0, stream>>>(l1_ew1, B1e);
  k_reorder_e<<<1, 512, 0, stream>>>(l2_ew1, B2e);

  k_root<32, 64, false><<<(NN * 64 + 255) / 256, 256, 0, stream>>>(x, l1_root, l1_bias, P1);
  k_edge<32, 64, false><<<NE / 64, 512, 0, stream>>>(src, dst, eattr, B1e, l1_eb1, B1, l1_eb2, x, P1);
  k_root<64, 32, true><<<(NN * 32 + 255) / 256, 256, 0, stream>>>(P1, l2_root, l2_bias, outf);
  k_edge<64, 32, true><<<NE / 64, 512, 0, stream>>>(src, dst, eattr, B2e, l2_eb1, B2, l2_eb2, P1, outf);
}